// Round 2
// baseline (163.182 us; speedup 1.0000x reference)
//
#include <hip/hip_runtime.h>

// rosa_4bit_layer: causal linear attention with per-head 4x4 state.
//   S_t = S_{t-1} + k_t v_t^T ;  o_t = q_t^T S_t ;  out = o * emb
// Shapes: x{q,k,v}: (B=4, T=4096, C=512) fp32, emb: (1,1,512) fp32.
// H = 128 heads, head_dim = 4 (contiguous 4-float groups in C).
//
// Two-dispatch structure (cooperative launch failed at runtime in R1 —
// output never written — so no grid.sync() anywhere):
//   Kernel 1: per-chunk aggregate S_chunk = sum_t k_t v_t^T per head
//             -> 4 MiB of aggregates in d_ws (L2/L3-resident after this).
//   Kernel 2: each block SUMS aggregates of chunks 0..c-1 itself
//             (coalesced float4 loads from the L2-hot 4 MiB buffer;
//             ~260 MB of L2-side traffic total ~= 7.6 us aggregate,
//             replacing the old 128-step serial-latency scan kernel
//             ~40 us + a dispatch drain), then replays its chunk and
//             writes out.
// State stored column-major: part[bc*2048 + tid*4 + d] = S[d][e] for
// thread (h,e): each thread owns one float4 column of its head's state.

constexpr int B  = 4;
constexpr int T  = 4096;
constexpr int C  = 512;
constexpr int CT = 32;       // timesteps per chunk
constexpr int NC = T / CT;   // 128 chunks per sequence
constexpr int NBLK = B * NC; // 512 blocks
// part: B*NC*2048 floats = 4 MiB in d_ws (harness ws is larger).

__global__ __launch_bounds__(512) void k_partial(const float* __restrict__ k,
                                                 const float* __restrict__ v,
                                                 float* __restrict__ part) {
  const int bc  = blockIdx.x;            // b*NC + c
  const int b   = bc / NC;
  const int c   = bc % NC;
  const int tid = threadIdx.x;           // 0..511
  const int h   = tid >> 2;
  const int e   = tid & 3;
  const int t0  = c * CT;

  const size_t base = ((size_t)b * T + t0) * (size_t)C + (h << 2);
  const float* kb = k + base;
  const float* vb = v + base + e;

  float4 acc = {0.f, 0.f, 0.f, 0.f};
#pragma unroll 8
  for (int t = 0; t < CT; ++t) {
    const float4 k4 = *reinterpret_cast<const float4*>(kb + (size_t)t * C);
    const float  ve = vb[(size_t)t * C];
    acc.x += k4.x * ve;
    acc.y += k4.y * ve;
    acc.z += k4.z * ve;
    acc.w += k4.w * ve;
  }
  reinterpret_cast<float4*>(part)[(size_t)bc * 512 + tid] = acc;
}

__global__ __launch_bounds__(512, 4) void k_out(const float* __restrict__ q,
                                                const float* __restrict__ k,
                                                const float* __restrict__ v,
                                                const float* __restrict__ emb,
                                                const float* __restrict__ part,
                                                float* __restrict__ out) {
  const int bc  = blockIdx.x;
  const int b   = bc / NC;
  const int c   = bc % NC;
  const int tid = threadIdx.x;
  const int h   = tid >> 2;
  const int e   = tid & 3;
  const int t0  = c * CT;

  // ---- chunk-start state: sum aggregates of chunks 0..c-1 ----
  // Coalesced: 512 threads x 16B = one contiguous 8 KB row per cc.
  // Source is the 4 MiB part buffer, L2/L3-hot after kernel 1.
  const float4* part4 = reinterpret_cast<const float4*>(part);
  const size_t  pb    = (size_t)b * NC * 512 + tid;
  float4 S = {0.f, 0.f, 0.f, 0.f};
#pragma unroll 4
  for (int cc = 0; cc < c; ++cc) {
    const float4 a = part4[pb + (size_t)cc * 512];
    S.x += a.x;
    S.y += a.y;
    S.z += a.z;
    S.w += a.w;
  }

  // ---- replay chunk from its start state ----
  const size_t base = ((size_t)b * T + t0) * (size_t)C + (h << 2);
  const float* qb = q + base;
  const float* kb = k + base;
  const float* vb = v + base + e;
  float*       ob = out + base + e;
  const float embv = emb[(h << 2) + e];

#pragma unroll 8
  for (int t = 0; t < CT; ++t) {
    const float4 k4 = *reinterpret_cast<const float4*>(kb + (size_t)t * C);
    const float4 q4 = *reinterpret_cast<const float4*>(qb + (size_t)t * C);
    const float  ve = vb[(size_t)t * C];
    S.x += k4.x * ve;
    S.y += k4.y * ve;
    S.z += k4.z * ve;
    S.w += k4.w * ve;
    const float o = q4.x * S.x + q4.y * S.y + q4.z * S.z + q4.w * S.w;
    ob[(size_t)t * C] = o * embv;
  }
}

extern "C" void kernel_launch(void* const* d_in, const int* in_sizes, int n_in,
                              void* d_out, int out_size, void* d_ws, size_t ws_size,
                              hipStream_t stream) {
  const float* xq  = (const float*)d_in[0];
  const float* xk  = (const float*)d_in[1];
  const float* xv  = (const float*)d_in[2];
  const float* emb = (const float*)d_in[3];
  float* out  = (float*)d_out;
  float* part = (float*)d_ws;   // B*NC*2048 floats = 4 MiB

  k_partial<<<NBLK, 512, 0, stream>>>(xk, xv, part);
  k_out<<<NBLK, 512, 0, stream>>>(xq, xk, xv, emb, part, out);
}

// Round 3
// 146.934 us; speedup vs baseline: 1.1106x; 1.1106x over previous
//
#include <hip/hip_runtime.h>

// rosa_4bit_layer: causal linear attention with per-head 4x4 state.
//   S_t = S_{t-1} + k_t v_t^T ;  o_t = q_t^T S_t ;  out = o * emb
// Shapes: x{q,k,v}: (B=4, T=4096, C=512) fp32, emb: (1,1,512) fp32.
// H = 128 heads, head_dim = 4 (contiguous 4-float groups in C).
//
// R2 post-mortem: in-kernel O(c) prefix reduction made k_out latency-bound
// (2 TB/s, 26% occupancy, imbalanced tail). R3: three uniform dispatches,
// all sized for FULL occupancy (CT=16 -> 1024 blocks x 8 waves = 4
// blocks/CU = 32 waves/CU = 100%), prefix scan done once in parallel.
//   K1 k_partial: per-chunk aggregates S_chunk -> 8 MiB in d_ws
//   K2 k_scan:    parallel exclusive scan over the 256 chunks per seq
//                 (batched 32-deep strided loads + LDS cross-group scan)
//   K3 k_out:     load chunk-start state (1 float4/thread), replay chunk,
//                 write out. Uniform work per block, no prefix loop.
// State stored column-major: part[bc*2048 + tid*4 + d] = S[d][e] for
// thread (h,e): each thread owns one float4 column of its head's state.

constexpr int B  = 4;
constexpr int T  = 4096;
constexpr int C  = 512;
constexpr int CT = 16;       // timesteps per chunk (16 -> 100% occupancy)
constexpr int NC = T / CT;   // 256 chunks per sequence
constexpr int NBLK = B * NC; // 1024 blocks
// part: B*NC*2048 floats = 8 MiB in d_ws (harness ws is larger).

__global__ __launch_bounds__(512, 8) void k_partial(const float* __restrict__ k,
                                                    const float* __restrict__ v,
                                                    float* __restrict__ part) {
  const int bc  = blockIdx.x;            // b*NC + c
  const int b   = bc >> 8;               // / NC
  const int c   = bc & (NC - 1);
  const int tid = threadIdx.x;           // 0..511
  const int h   = tid >> 2;
  const int e   = tid & 3;
  const int t0  = c * CT;

  const size_t base = ((size_t)b * T + t0) * (size_t)C + (h << 2);
  const float* kb = k + base;
  const float* vb = v + base + e;

  float4 acc = {0.f, 0.f, 0.f, 0.f};
#pragma unroll
  for (int t = 0; t < CT; ++t) {
    const float4 k4 = *reinterpret_cast<const float4*>(kb + (size_t)t * C);
    const float  ve = vb[(size_t)t * C];
    acc.x += k4.x * ve;
    acc.y += k4.y * ve;
    acc.z += k4.z * ve;
    acc.w += k4.w * ve;
  }
  reinterpret_cast<float4*>(part)[(size_t)bc * 512 + tid] = acc;
}

// Parallel exclusive scan over chunks. Grid: B*32 = 128 blocks, 512 thr.
// Per (b, j) column (j in [0,2048)): NC=256 values at stride 2048 floats.
// Block = one b, one 64-wide j tile; threads = 8 c-groups x 64 j lanes.
// Each thread: 32 batched independent strided loads (coalesced 256B/wave),
// local serial scan, LDS scan across the 8 groups (2-way bank alias: free).
__global__ __launch_bounds__(512, 4) void k_scan(float* __restrict__ part) {
  const int sb = blockIdx.x >> 5;        // sequence b
  const int jt = blockIdx.x & 31;        // j tile
  const int tid = threadIdx.x;
  const int jl = tid & 63;               // j within tile (coalesced lanes)
  const int ci = tid >> 6;               // c-group 0..7 (wave-uniform)
  const int j  = (jt << 6) + jl;
  float* basep = part + (size_t)sb * NC * 2048 + j;
  const int c0 = ci * 32;

  float vals[32];
#pragma unroll
  for (int i = 0; i < 32; ++i) vals[i] = basep[(size_t)(c0 + i) * 2048];
  float sum = 0.f;
#pragma unroll
  for (int i = 0; i < 32; ++i) sum += vals[i];

  __shared__ float lsum[8][64];
  lsum[ci][jl] = sum;
  __syncthreads();
  float run = 0.f;
#pragma unroll
  for (int g = 0; g < 7; ++g)
    if (g < ci) run += lsum[g][jl];      // ci wave-uniform: no divergence
#pragma unroll
  for (int i = 0; i < 32; ++i) {
    basep[(size_t)(c0 + i) * 2048] = run;  // exclusive prefix
    run += vals[i];
  }
}

__global__ __launch_bounds__(512, 8) void k_out(const float* __restrict__ q,
                                                const float* __restrict__ k,
                                                const float* __restrict__ v,
                                                const float* __restrict__ emb,
                                                const float* __restrict__ part,
                                                float* __restrict__ out) {
  const int bc  = blockIdx.x;
  const int b   = bc >> 8;
  const int c   = bc & (NC - 1);
  const int tid = threadIdx.x;
  const int h   = tid >> 2;
  const int e   = tid & 3;
  const int t0  = c * CT;

  // chunk-start state: one coalesced float4 per thread
  float4 S = reinterpret_cast<const float4*>(part)[(size_t)bc * 512 + tid];

  const size_t base = ((size_t)b * T + t0) * (size_t)C + (h << 2);
  const float* qb = q + base;
  const float* kb = k + base;
  const float* vb = v + base + e;
  float*       ob = out + base + e;
  const float embv = emb[(h << 2) + e];

#pragma unroll
  for (int t = 0; t < CT; ++t) {
    const float4 k4 = *reinterpret_cast<const float4*>(kb + (size_t)t * C);
    const float4 q4 = *reinterpret_cast<const float4*>(qb + (size_t)t * C);
    const float  ve = vb[(size_t)t * C];
    S.x += k4.x * ve;
    S.y += k4.y * ve;
    S.z += k4.z * ve;
    S.w += k4.w * ve;
    const float o = q4.x * S.x + q4.y * S.y + q4.z * S.z + q4.w * S.w;
    ob[(size_t)t * C] = o * embv;
  }
}

extern "C" void kernel_launch(void* const* d_in, const int* in_sizes, int n_in,
                              void* d_out, int out_size, void* d_ws, size_t ws_size,
                              hipStream_t stream) {
  const float* xq  = (const float*)d_in[0];
  const float* xk  = (const float*)d_in[1];
  const float* xv  = (const float*)d_in[2];
  const float* emb = (const float*)d_in[3];
  float* out  = (float*)d_out;
  float* part = (float*)d_ws;   // B*NC*2048 floats = 8 MiB

  k_partial<<<NBLK, 512, 0, stream>>>(xk, xv, part);
  k_scan<<<B * 32, 512, 0, stream>>>(part);
  k_out<<<NBLK, 512, 0, stream>>>(xq, xk, xv, emb, part, out);
}